// Round 1
// baseline (823.623 us; speedup 1.0000x reference)
//
#include <hip/hip_runtime.h>

#define DEV_INLINE __device__ __forceinline__

constexpr int NF = 26;   // input features
constexpr int H1 = 24;   // layer-1 hidden
constexpr int H2 = 8;    // layer-2 hidden
constexpr int T  = 5;    // sequence length

DEV_INLINE float fast_rcp(float x) { return __builtin_amdgcn_rcpf(x); }
// sigmoid(x) = 1/(1+exp(-x))
DEV_INLINE float fast_sigmoid(float x) { return fast_rcp(1.0f + __expf(-x)); }
// tanh(x) = 2/(1+exp(-2x)) - 1
DEV_INLINE float fast_tanh(float x) {
    return fmaf(2.0f, fast_rcp(1.0f + __expf(-2.0f * x)), -1.0f);
}

__global__ __launch_bounds__(256) void lstm2_fused(
    const float* __restrict__ x,
    const float* __restrict__ w_ih1, const float* __restrict__ w_hh1,
    const float* __restrict__ b_ih1, const float* __restrict__ b_hh1,
    const float* __restrict__ w_ih2, const float* __restrict__ w_hh2,
    const float* __restrict__ b_ih2, const float* __restrict__ b_hh2,
    float* __restrict__ out, int batch)
{
    const int b = blockIdx.x * blockDim.x + threadIdx.x;
    if (b >= batch) return;
    const float* __restrict__ xb = x + (size_t)b * (T * NF);

    float h1[H1], c1[H1];
    float h2v[H2], c2[H2];
    #pragma unroll
    for (int j = 0; j < H1; ++j) { h1[j] = 0.0f; c1[j] = 0.0f; }
    #pragma unroll
    for (int j = 0; j < H2; ++j) { h2v[j] = 0.0f; c2[j] = 0.0f; }

    for (int t = 0; t < T; ++t) {
        // ---- load x_t (26 floats, 8B-aligned) ----
        float xt[NF];
        const float2* xp = reinterpret_cast<const float2*>(xb + t * NF);
        #pragma unroll
        for (int i = 0; i < NF / 2; ++i) {
            float2 v = xp[i];
            xt[2 * i] = v.x;
            xt[2 * i + 1] = v.y;
        }

        // ---- layer 1 ----
        float h1n[H1];
        #pragma unroll
        for (int j = 0; j < H1; ++j) {
            float ai = b_ih1[j]          + b_hh1[j];
            float af = b_ih1[H1 + j]     + b_hh1[H1 + j];
            float ag = b_ih1[2 * H1 + j] + b_hh1[2 * H1 + j];
            float ao = b_ih1[3 * H1 + j] + b_hh1[3 * H1 + j];
            #pragma unroll
            for (int i = 0; i < NF; ++i) {
                const float xi = xt[i];
                ai = fmaf(w_ih1[(j) * NF + i],          xi, ai);
                af = fmaf(w_ih1[(H1 + j) * NF + i],     xi, af);
                ag = fmaf(w_ih1[(2 * H1 + j) * NF + i], xi, ag);
                ao = fmaf(w_ih1[(3 * H1 + j) * NF + i], xi, ao);
            }
            if (t > 0) {  // h1 == 0 at t==0: recurrent part contributes exactly 0
                #pragma unroll
                for (int k = 0; k < H1; ++k) {
                    const float hk = h1[k];
                    ai = fmaf(w_hh1[(j) * H1 + k],          hk, ai);
                    af = fmaf(w_hh1[(H1 + j) * H1 + k],     hk, af);
                    ag = fmaf(w_hh1[(2 * H1 + j) * H1 + k], hk, ag);
                    ao = fmaf(w_hh1[(3 * H1 + j) * H1 + k], hk, ao);
                }
            }
            const float ig = fast_sigmoid(ai);
            const float fg = fast_sigmoid(af);
            const float gg = fast_tanh(ag);
            const float og = fast_sigmoid(ao);
            const float c  = fmaf(fg, c1[j], ig * gg);  // c1==0 at t==0: exact
            c1[j]  = c;
            h1n[j] = og * fast_tanh(c);
        }
        #pragma unroll
        for (int j = 0; j < H1; ++j) h1[j] = h1n[j];

        // ---- layer 2 (consumes h1 of this timestep) ----
        float h2n[H2];
        #pragma unroll
        for (int j = 0; j < H2; ++j) {
            float ai = b_ih2[j]          + b_hh2[j];
            float af = b_ih2[H2 + j]     + b_hh2[H2 + j];
            float ag = b_ih2[2 * H2 + j] + b_hh2[2 * H2 + j];
            float ao = b_ih2[3 * H2 + j] + b_hh2[3 * H2 + j];
            #pragma unroll
            for (int k = 0; k < H1; ++k) {
                const float hk = h1[k];
                ai = fmaf(w_ih2[(j) * H1 + k],          hk, ai);
                af = fmaf(w_ih2[(H2 + j) * H1 + k],     hk, af);
                ag = fmaf(w_ih2[(2 * H2 + j) * H1 + k], hk, ag);
                ao = fmaf(w_ih2[(3 * H2 + j) * H1 + k], hk, ao);
            }
            if (t > 0) {
                #pragma unroll
                for (int k = 0; k < H2; ++k) {
                    const float hk = h2v[k];
                    ai = fmaf(w_hh2[(j) * H2 + k],          hk, ai);
                    af = fmaf(w_hh2[(H2 + j) * H2 + k],     hk, af);
                    ag = fmaf(w_hh2[(2 * H2 + j) * H2 + k], hk, ag);
                    ao = fmaf(w_hh2[(3 * H2 + j) * H2 + k], hk, ao);
                }
            }
            const float ig = fast_sigmoid(ai);
            const float fg = fast_sigmoid(af);
            const float gg = fast_tanh(ag);
            const float og = fast_sigmoid(ao);
            const float c  = fmaf(fg, c2[j], ig * gg);
            c2[j]  = c;
            h2n[j] = og * fast_tanh(c);
        }
        #pragma unroll
        for (int j = 0; j < H2; ++j) h2v[j] = h2n[j];
    }

    // ---- write final h2: 32 contiguous bytes per thread, coalesced ----
    float4* op = reinterpret_cast<float4*>(out + (size_t)b * H2);
    op[0] = make_float4(h2v[0], h2v[1], h2v[2], h2v[3]);
    op[1] = make_float4(h2v[4], h2v[5], h2v[6], h2v[7]);
}

extern "C" void kernel_launch(void* const* d_in, const int* in_sizes, int n_in,
                              void* d_out, int out_size, void* d_ws, size_t ws_size,
                              hipStream_t stream)
{
    const float* x     = (const float*)d_in[0];
    const float* w_ih1 = (const float*)d_in[1];
    const float* w_hh1 = (const float*)d_in[2];
    const float* b_ih1 = (const float*)d_in[3];
    const float* b_hh1 = (const float*)d_in[4];
    const float* w_ih2 = (const float*)d_in[5];
    const float* w_hh2 = (const float*)d_in[6];
    const float* b_ih2 = (const float*)d_in[7];
    const float* b_hh2 = (const float*)d_in[8];
    float* out = (float*)d_out;

    const int batch = in_sizes[0] / (T * NF);
    const int block = 256;
    const int grid  = (batch + block - 1) / block;
    lstm2_fused<<<grid, block, 0, stream>>>(x, w_ih1, w_hh1, b_ih1, b_hh1,
                                            w_ih2, w_hh2, b_ih2, b_hh2,
                                            out, batch);
}